// Round 19
// baseline (113.560 us; speedup 1.0000x reference)
//
#include <hip/hip_runtime.h>

typedef __attribute__((ext_vector_type(8))) short  short8;
typedef __attribute__((ext_vector_type(4))) float  f32x4;
typedef __attribute__((ext_vector_type(2))) float  f32x2;

#define CIN 32
#define COUT 32
#define DD 32
#define HH 48
#define WW 48
#define NTAP 27
#define SPATIAL (DD*HH*WW)          // 73728

// ---- ws layout (bytes) ----
#define BP2_ELEMS (27*6*64*8)                       // conv B-pack: 82944
#define OFF_WPK   ((size_t)BP2_ELEMS*2)             // 165888
#define WPK_ELEMS (27*2*64*8)                       // einsum B-pack: 27648
#define OFF_XT    (OFF_WPK + (size_t)WPK_ELEMS*2)   // 221184 (16B aligned)
// xT bf16: 4,718,592 B -> total ~4.94 MB

#define SB0() __builtin_amdgcn_sched_barrier(0)

__device__ __forceinline__ unsigned short f2bf(float f) {
    union { float f; unsigned u; } v; v.f = f;
    unsigned r = v.u + 0x7FFFu + ((v.u >> 16) & 1u);   // RNE
    return (unsigned short)(r >> 16);
}
__device__ __forceinline__ float bitsf(unsigned u) {
    union { unsigned u; float f; } v; v.u = u; return v.f;
}

// -------------------- merged prep kernel (1152 blocks x 256) ------------------
__global__ __launch_bounds__(256) void prep_all(
        const float* __restrict__ x,
        const float* __restrict__ w_off,
        const float* __restrict__ w_def,
        unsigned short* __restrict__ Bp2,
        unsigned short* __restrict__ wpk,
        unsigned short* __restrict__ xT)
{
    const int bid = blockIdx.x;
    const int tid = threadIdx.x;

    if (bid < 324) {                           // conv B-pack: 324*256 = 82944
        int i = bid * 256 + tid;
        int e    = i & 7;
        int lane = (i >> 3) & 63;
        int j    = (i >> 9) % 6;
        int n    = i / (512 * 6);
        int col = lane & 15, kg = lane >> 4;
        int oc = j * 16 + col, c = kg * 8 + e;
        float v = (oc < 81) ? w_off[((size_t)oc * CIN + c) * NTAP + n] : 0.f;
        Bp2[i] = f2bf(v);
    } else if (bid < 432) {                    // einsum B-pack: 108*256 = 27648
        int i = (bid - 324) * 256 + tid;
        int e    = i & 7;
        int lane = (i >> 3) & 63;
        int half = (i >> 9) & 1;
        int n    = i >> 10;
        int kg = lane >> 4, col = lane & 15;
        int c  = kg * 8 + e, oc = half * 16 + col;
        wpk[i] = f2bf(w_def[((size_t)oc * CIN + c) * NTAP + n]);
    }

    // x transpose (all blocks)
    __shared__ float t[CIN][65];
    const int p0 = bid * 64;
    const int tx = tid & 63, ty = tid >> 6;
    #pragma unroll
    for (int k = 0; k < 8; ++k) {
        int c = ty + k * 4;
        t[c][tx] = x[(size_t)c * SPATIAL + p0 + tx];
    }
    __syncthreads();
    const int pl = tid >> 2, cg = (tid & 3) * 8;
    short8 v;
    #pragma unroll
    for (int i = 0; i < 8; ++i) v[i] = (short)f2bf(t[cg + i][pl]);
    *(short8*)&xT[((size_t)(p0 + pl)) * 32 + cg] = v;
}

// ---------------------------------------------------------------- gather buf
struct Gath {
    uint4 cw[8];
    float gg[8];
};

__device__ __forceinline__ void tap_issue(
        Gath& tb, const uint4* __restrict__ Xu,
        float od, float oh, float ow,
        int n, int d, int h, int w, int kg)
{
    float rd = (float)(n / 9) - 1.f;
    float rh = (float)((n / 3) % 3) - 1.f;
    float rw = (float)(n % 3) - 1.f;

    float pdp = (float)(d + 1) + rd + od;
    float php = (float)(h + 1) + rh + oh;
    float pwp = (float)(w + 1) + rw + ow;

    float fd = floorf(pdp), fh = floorf(php), fw = floorf(pwp);
    float qd0 = fminf(fmaxf(fd,       0.f), 33.f);
    float qd1 = fminf(fmaxf(fd + 1.f, 0.f), 33.f);
    float qh0 = fminf(fmaxf(fh,       0.f), 49.f);
    float qh1 = fminf(fmaxf(fh + 1.f, 0.f), 49.f);
    float qw0 = fminf(fmaxf(fw,       0.f), 49.f);
    float qw1 = fminf(fmaxf(fw + 1.f, 0.f), 49.f);
    float pcd = fminf(fmaxf(pdp, 0.f), 33.f);
    float pch = fminf(fmaxf(php, 0.f), 49.f);
    float pcw = fminf(fmaxf(pwp, 0.f), 49.f);

    float gd0 = 1.f + (qd0 - pcd), gd1 = 1.f - (qd1 - pcd);
    float gh0 = 1.f + (qh0 - pch), gh1 = 1.f - (qh1 - pch);
    float gw0 = 1.f + (qw0 - pcw), gw1 = 1.f - (qw1 - pcw);
    // pad-corner semantics: zero per-axis gain, clamp index to real range
    gd0 = (qd0 >= 1.f && qd0 <= 32.f) ? gd0 : 0.f;
    gd1 = (qd1 >= 1.f && qd1 <= 32.f) ? gd1 : 0.f;
    gh0 = (qh0 >= 1.f && qh0 <= 48.f) ? gh0 : 0.f;
    gh1 = (qh1 >= 1.f && qh1 <= 48.f) ? gh1 : 0.f;
    gw0 = (qw0 >= 1.f && qw0 <= 48.f) ? gw0 : 0.f;
    gw1 = (qw1 >= 1.f && qw1 <= 48.f) ? gw1 : 0.f;
    int zd0 = (int)fminf(fmaxf(qd0, 1.f), 32.f) - 1;
    int zd1 = (int)fminf(fmaxf(qd1, 1.f), 32.f) - 1;
    int zh0 = (int)fminf(fmaxf(qh0, 1.f), 48.f) - 1;
    int zh1 = (int)fminf(fmaxf(qh1, 1.f), 48.f) - 1;
    int zw0 = (int)fminf(fmaxf(qw0, 1.f), 48.f) - 1;
    int zw1 = (int)fminf(fmaxf(qw1, 1.f), 48.f) - 1;

    int bd0 = zd0 * 2304, bd1 = zd1 * 2304;
    int bh0 = zh0 * 48,   bh1 = zh1 * 48;
    float gdh00 = gd0 * gh0, gdh01 = gd0 * gh1;
    float gdh10 = gd1 * gh0, gdh11 = gd1 * gh1;

    tb.cw[0] = Xu[(size_t)(bd0 + bh0 + zw0) * 4 + kg];
    tb.cw[1] = Xu[(size_t)(bd0 + bh0 + zw1) * 4 + kg];
    tb.cw[2] = Xu[(size_t)(bd0 + bh1 + zw0) * 4 + kg];
    tb.cw[3] = Xu[(size_t)(bd0 + bh1 + zw1) * 4 + kg];
    tb.cw[4] = Xu[(size_t)(bd1 + bh0 + zw0) * 4 + kg];
    tb.cw[5] = Xu[(size_t)(bd1 + bh0 + zw1) * 4 + kg];
    tb.cw[6] = Xu[(size_t)(bd1 + bh1 + zw0) * 4 + kg];
    tb.cw[7] = Xu[(size_t)(bd1 + bh1 + zw1) * 4 + kg];

    tb.gg[0] = gdh00 * gw0;  tb.gg[1] = gdh00 * gw1;
    tb.gg[2] = gdh01 * gw0;  tb.gg[3] = gdh01 * gw1;
    tb.gg[4] = gdh10 * gw0;  tb.gg[5] = gdh10 * gw1;
    tb.gg[6] = gdh11 * gw0;  tb.gg[7] = gdh11 * gw1;
}

__device__ __forceinline__ void tap_consume(
        const Gath& tb, short8 b0, short8 b1, f32x4& acc0, f32x4& acc1)
{
    f32x2 xa0 = {0.f, 0.f}, xa1 = {0.f, 0.f};
    f32x2 xa2 = {0.f, 0.f}, xa3 = {0.f, 0.f};

    #pragma unroll
    for (int e = 0; e < 8; ++e) {
        uint4 cw = tb.cw[e];
        f32x2 g2 = {tb.gg[e], tb.gg[e]};
        f32x2 v0 = {bitsf(cw.x << 16), bitsf(cw.x & 0xFFFF0000u)};
        f32x2 v1 = {bitsf(cw.y << 16), bitsf(cw.y & 0xFFFF0000u)};
        f32x2 v2 = {bitsf(cw.z << 16), bitsf(cw.z & 0xFFFF0000u)};
        f32x2 v3 = {bitsf(cw.w << 16), bitsf(cw.w & 0xFFFF0000u)};
        asm("v_pk_fma_f32 %0, %1, %2, %0" : "+v"(xa0) : "v"(v0), "v"(g2));
        asm("v_pk_fma_f32 %0, %1, %2, %0" : "+v"(xa1) : "v"(v1), "v"(g2));
        asm("v_pk_fma_f32 %0, %1, %2, %0" : "+v"(xa2) : "v"(v2), "v"(g2));
        asm("v_pk_fma_f32 %0, %1, %2, %0" : "+v"(xa3) : "v"(v3), "v"(g2));
    }

    union { unsigned u[4]; short8 s; } av;
    asm("v_cvt_pk_bf16_f32 %0, %1, %2" : "=v"(av.u[0]) : "v"(xa0.x), "v"(xa0.y));
    asm("v_cvt_pk_bf16_f32 %0, %1, %2" : "=v"(av.u[1]) : "v"(xa1.x), "v"(xa1.y));
    asm("v_cvt_pk_bf16_f32 %0, %1, %2" : "=v"(av.u[2]) : "v"(xa2.x), "v"(xa2.y));
    asm("v_cvt_pk_bf16_f32 %0, %1, %2" : "=v"(av.u[3]) : "v"(xa3.x), "v"(xa3.y));

    acc0 = __builtin_amdgcn_mfma_f32_16x16x32_bf16(av.s, b0, acc0, 0, 0, 0);
    acc1 = __builtin_amdgcn_mfma_f32_16x16x32_bf16(av.s, b1, acc1, 0, 0, 0);
}

// ---------------- Fused kernel, M=2 tiles/wave, 3-wave blocks (96 pos)
// Phase 3 uses a 2-buffer one-tap-lookahead rotation: consume gX(n) is
// immediately followed by issue gX(n+1) (WAR dependence pins the order),
// so every consume's loads were issued one full iteration (~300cy) earlier.
__global__ __launch_bounds__(192, 3) void fused_deform13(
        const unsigned short* __restrict__ xT,    // [SPATIAL][32] bf16
        const unsigned short* __restrict__ Bp2,
        const unsigned short* __restrict__ wpk,
        float* __restrict__ out)                  // [32][SPATIAL] f32
{
    __shared__ float offl[3][2][16][82];          // 31.5 KB (cols 0..80 read)

    // bijective XCD swizzle: 768 blocks = 8 XCDs x 96 contiguous
    const int bid  = (int)blockIdx.x;
    const int sbid = (bid & 7) * 96 + (bid >> 3);

    const int tid  = threadIdx.x;
    const int lane = tid & 63, wv = tid >> 6;     // wv in 0..2
    const int p0   = sbid * 96 + wv * 32;
    const int kg   = lane >> 4;
    const int row  = lane & 15;
    const int pos0 = p0 + row;
    const int pos1 = p0 + 16 + row;
    const int w0c = pos0 % WW, h0c = (pos0 / WW) % HH, d0c = pos0 / (WW * HH);
    const int w1c = pos1 % WW, h1c = (pos1 / WW) % HH, d1c = pos1 / (WW * HH);

    const uint4* Xu = (const uint4*)xT;
    const uint4* Bu = (const uint4*)Bp2;
    const uint4* Wu = (const uint4*)wpk;

    // ---------------- phase 1: offset conv, B shared across 2 tiles ----------
    f32x4 cacc0[6], cacc1[6];
    #pragma unroll
    for (int j = 0; j < 6; ++j) {
        cacc0[j] = (f32x4){0.f, 0.f, 0.f, 0.f};
        cacc1[j] = (f32x4){0.f, 0.f, 0.f, 0.f};
    }

    {
        #pragma unroll 1
        for (int n = 0; n < NTAP; ++n) {
            int td = n / 9, th = (n / 3) % 3, tw = n % 3;
            int dis = (td - 1) * 2304 + (th - 1) * 48 + (tw - 1);
            int v0 = ((unsigned)(d0c + td - 1) < DD) & ((unsigned)(h0c + th - 1) < HH)
                   & ((unsigned)(w0c + tw - 1) < WW);
            int v1 = ((unsigned)(d1c + td - 1) < DD) & ((unsigned)(h1c + th - 1) < HH)
                   & ((unsigned)(w1c + tw - 1) < WW);
            uint4 a0 = Xu[(size_t)(v0 ? pos0 + dis : pos0) * 4 + kg];
            uint4 a1 = Xu[(size_t)(v1 ? pos1 + dis : pos1) * 4 + kg];
            uint4 wt[6];
            #pragma unroll
            for (int j = 0; j < 6; ++j)
                wt[j] = Bu[(size_t)(n * 6 + j) * 64 + lane];
            SB0();
            if (!v0) { a0.x = 0; a0.y = 0; a0.z = 0; a0.w = 0; }
            if (!v1) { a1.x = 0; a1.y = 0; a1.z = 0; a1.w = 0; }
            union { uint4 u; short8 s; } av0, av1, b;
            av0.u = a0; av1.u = a1;
            #pragma unroll
            for (int j = 0; j < 6; ++j) {
                b.u = wt[j];
                cacc0[j] = __builtin_amdgcn_mfma_f32_16x16x32_bf16(av0.s, b.s, cacc0[j], 0, 0, 0);
                cacc1[j] = __builtin_amdgcn_mfma_f32_16x16x32_bf16(av1.s, b.s, cacc1[j], 0, 0, 0);
            }
        }
    }

    // ---------------- phase 2: D-frags -> wave-local LDS ----------------
    #pragma unroll
    for (int j = 0; j < 6; ++j) {
        int col = j * 16 + row;
        if (col < 81) {
            #pragma unroll
            for (int r = 0; r < 4; ++r) {
                offl[wv][0][kg * 4 + r][col] = cacc0[j][r];
                offl[wv][1][kg * 4 + r][col] = cacc1[j][r];
            }
        }
    }
    __syncthreads();

    // ---------------- phase 3: 2-buffer one-tap-lookahead rotation ------------
    const float* ol0 = &offl[wv][0][row][0];
    const float* ol1 = &offl[wv][1][row][0];

    f32x4 acc00 = {0.f, 0.f, 0.f, 0.f}, acc01 = {0.f, 0.f, 0.f, 0.f};
    f32x4 acc10 = {0.f, 0.f, 0.f, 0.f}, acc11 = {0.f, 0.f, 0.f, 0.f};

    {
        Gath gA, gB;   // gA <-> tile0, gB <-> tile1, rotated one tap ahead
        tap_issue(gA, Xu, ol0[0], ol0[27], ol0[54], 0, d0c, h0c, w0c, kg);
        SB0();
        tap_issue(gB, Xu, ol1[0], ol1[27], ol1[54], 0, d1c, h1c, w1c, kg);
        SB0();

        #pragma unroll 1
        for (int n = 0; n < NTAP; ++n) {
            int np = (n + 1 < NTAP) ? n + 1 : NTAP - 1;   // clamped (last iter re-issues tap 26)
            union { uint4 u; short8 s; } b0, b1;
            b0.u = Wu[(size_t)(n * 2 + 0) * 64 + lane];
            b1.u = Wu[(size_t)(n * 2 + 1) * 64 + lane];
            // consume tile0 tap n (issued one iteration ago), refill for tap n+1
            tap_consume(gA, b0.s, b1.s, acc00, acc01);
            tap_issue(gA, Xu, ol0[np], ol0[27 + np], ol0[54 + np], np, d0c, h0c, w0c, kg);
            SB0();
            // consume tile1 tap n, refill for tap n+1
            tap_consume(gB, b0.s, b1.s, acc10, acc11);
            tap_issue(gB, Xu, ol1[np], ol1[27 + np], ol1[54 + np], np, d1c, h1c, w1c, kg);
            SB0();
        }
        // final clamped issues (tap 26 re-issued) are redundant, never consumed.
    }

    // D layout: col = lane&15 -> oc, row = kg*4+reg -> pos
    const int pb0 = p0 + kg * 4;
    const int pb1 = p0 + 16 + kg * 4;
    *(f32x4*)&out[(size_t)row        * SPATIAL + pb0] = acc00;
    *(f32x4*)&out[(size_t)(16 + row) * SPATIAL + pb0] = acc01;
    *(f32x4*)&out[(size_t)row        * SPATIAL + pb1] = acc10;
    *(f32x4*)&out[(size_t)(16 + row) * SPATIAL + pb1] = acc11;
}

// ----------------------------------------------------------------------------
extern "C" void kernel_launch(void* const* d_in, const int* in_sizes, int n_in,
                              void* d_out, int out_size, void* d_ws, size_t ws_size,
                              hipStream_t stream)
{
    const float* x     = (const float*)d_in[0];
    const float* w_off = (const float*)d_in[1];
    const float* w_def = (const float*)d_in[2];
    float* out = (float*)d_out;

    unsigned short* Bp2 = (unsigned short*)((char*)d_ws);
    unsigned short* wpk = (unsigned short*)((char*)d_ws + OFF_WPK);
    unsigned short* xT  = (unsigned short*)((char*)d_ws + OFF_XT);

    prep_all<<<SPATIAL / 64, 256, 0, stream>>>(x, w_off, w_def, Bp2, wpk, xT);
    fused_deform13<<<SPATIAL / 96, 192, 0, stream>>>(xT, Bp2, wpk, out);
}

// Round 20
// 112.234 us; speedup vs baseline: 1.0118x; 1.0118x over previous
//
#include <hip/hip_runtime.h>

typedef __attribute__((ext_vector_type(8))) short  short8;
typedef __attribute__((ext_vector_type(4))) float  f32x4;
typedef __attribute__((ext_vector_type(2))) float  f32x2;

#define CIN 32
#define COUT 32
#define DD 32
#define HH 48
#define WW 48
#define NTAP 27
#define SPATIAL (DD*HH*WW)          // 73728

// ---- ws layout (bytes) ----
#define BP2_ELEMS (27*6*64*8)                       // conv B-pack: 82944
#define OFF_WPK   ((size_t)BP2_ELEMS*2)             // 165888
#define WPK_ELEMS (27*2*64*8)                       // einsum B-pack: 27648
#define OFF_XT    (OFF_WPK + (size_t)WPK_ELEMS*2)   // 221184 (16B aligned)
// xT bf16: 4,718,592 B -> total ~4.94 MB

#define SB0() __builtin_amdgcn_sched_barrier(0)

__device__ __forceinline__ unsigned short f2bf(float f) {
    union { float f; unsigned u; } v; v.f = f;
    unsigned r = v.u + 0x7FFFu + ((v.u >> 16) & 1u);   // RNE
    return (unsigned short)(r >> 16);
}
__device__ __forceinline__ float bitsf(unsigned u) {
    union { unsigned u; float f; } v; v.u = u; return v.f;
}

// -------------------- merged prep kernel (1152 blocks x 256) ------------------
__global__ __launch_bounds__(256) void prep_all(
        const float* __restrict__ x,
        const float* __restrict__ w_off,
        const float* __restrict__ w_def,
        unsigned short* __restrict__ Bp2,
        unsigned short* __restrict__ wpk,
        unsigned short* __restrict__ xT)
{
    const int bid = blockIdx.x;
    const int tid = threadIdx.x;

    if (bid < 324) {                           // conv B-pack: 324*256 = 82944
        int i = bid * 256 + tid;
        int e    = i & 7;
        int lane = (i >> 3) & 63;
        int j    = (i >> 9) % 6;
        int n    = i / (512 * 6);
        int col = lane & 15, kg = lane >> 4;
        int oc = j * 16 + col, c = kg * 8 + e;
        float v = (oc < 81) ? w_off[((size_t)oc * CIN + c) * NTAP + n] : 0.f;
        Bp2[i] = f2bf(v);
    } else if (bid < 432) {                    // einsum B-pack: 108*256 = 27648
        int i = (bid - 324) * 256 + tid;
        int e    = i & 7;
        int lane = (i >> 3) & 63;
        int half = (i >> 9) & 1;
        int n    = i >> 10;
        int kg = lane >> 4, col = lane & 15;
        int c  = kg * 8 + e, oc = half * 16 + col;
        wpk[i] = f2bf(w_def[((size_t)oc * CIN + c) * NTAP + n]);
    }

    // x transpose (all blocks)
    __shared__ float t[CIN][65];
    const int p0 = bid * 64;
    const int tx = tid & 63, ty = tid >> 6;
    #pragma unroll
    for (int k = 0; k < 8; ++k) {
        int c = ty + k * 4;
        t[c][tx] = x[(size_t)c * SPATIAL + p0 + tx];
    }
    __syncthreads();
    const int pl = tid >> 2, cg = (tid & 3) * 8;
    short8 v;
    #pragma unroll
    for (int i = 0; i < 8; ++i) v[i] = (short)f2bf(t[cg + i][pl]);
    *(short8*)&xT[((size_t)(p0 + pl)) * 32 + cg] = v;
}

// ---------------------------------------------------------------- gather buf
struct Gath {
    uint4 cw[8];
    float gg[8];
};

__device__ __forceinline__ void tap_issue(
        Gath& tb, const uint4* __restrict__ Xu,
        float od, float oh, float ow,
        int n, int d, int h, int w, int kg)
{
    float rd = (float)(n / 9) - 1.f;
    float rh = (float)((n / 3) % 3) - 1.f;
    float rw = (float)(n % 3) - 1.f;

    float pdp = (float)(d + 1) + rd + od;
    float php = (float)(h + 1) + rh + oh;
    float pwp = (float)(w + 1) + rw + ow;

    float fd = floorf(pdp), fh = floorf(php), fw = floorf(pwp);
    float qd0 = fminf(fmaxf(fd,       0.f), 33.f);
    float qd1 = fminf(fmaxf(fd + 1.f, 0.f), 33.f);
    float qh0 = fminf(fmaxf(fh,       0.f), 49.f);
    float qh1 = fminf(fmaxf(fh + 1.f, 0.f), 49.f);
    float qw0 = fminf(fmaxf(fw,       0.f), 49.f);
    float qw1 = fminf(fmaxf(fw + 1.f, 0.f), 49.f);
    float pcd = fminf(fmaxf(pdp, 0.f), 33.f);
    float pch = fminf(fmaxf(php, 0.f), 49.f);
    float pcw = fminf(fmaxf(pwp, 0.f), 49.f);

    float gd0 = 1.f + (qd0 - pcd), gd1 = 1.f - (qd1 - pcd);
    float gh0 = 1.f + (qh0 - pch), gh1 = 1.f - (qh1 - pch);
    float gw0 = 1.f + (qw0 - pcw), gw1 = 1.f - (qw1 - pcw);
    // pad-corner semantics: zero per-axis gain, clamp index to real range
    gd0 = (qd0 >= 1.f && qd0 <= 32.f) ? gd0 : 0.f;
    gd1 = (qd1 >= 1.f && qd1 <= 32.f) ? gd1 : 0.f;
    gh0 = (qh0 >= 1.f && qh0 <= 48.f) ? gh0 : 0.f;
    gh1 = (qh1 >= 1.f && qh1 <= 48.f) ? gh1 : 0.f;
    gw0 = (qw0 >= 1.f && qw0 <= 48.f) ? gw0 : 0.f;
    gw1 = (qw1 >= 1.f && qw1 <= 48.f) ? gw1 : 0.f;
    int zd0 = (int)fminf(fmaxf(qd0, 1.f), 32.f) - 1;
    int zd1 = (int)fminf(fmaxf(qd1, 1.f), 32.f) - 1;
    int zh0 = (int)fminf(fmaxf(qh0, 1.f), 48.f) - 1;
    int zh1 = (int)fminf(fmaxf(qh1, 1.f), 48.f) - 1;
    int zw0 = (int)fminf(fmaxf(qw0, 1.f), 48.f) - 1;
    int zw1 = (int)fminf(fmaxf(qw1, 1.f), 48.f) - 1;

    int bd0 = zd0 * 2304, bd1 = zd1 * 2304;
    int bh0 = zh0 * 48,   bh1 = zh1 * 48;
    float gdh00 = gd0 * gh0, gdh01 = gd0 * gh1;
    float gdh10 = gd1 * gh0, gdh11 = gd1 * gh1;

    tb.cw[0] = Xu[(size_t)(bd0 + bh0 + zw0) * 4 + kg];
    tb.cw[1] = Xu[(size_t)(bd0 + bh0 + zw1) * 4 + kg];
    tb.cw[2] = Xu[(size_t)(bd0 + bh1 + zw0) * 4 + kg];
    tb.cw[3] = Xu[(size_t)(bd0 + bh1 + zw1) * 4 + kg];
    tb.cw[4] = Xu[(size_t)(bd1 + bh0 + zw0) * 4 + kg];
    tb.cw[5] = Xu[(size_t)(bd1 + bh0 + zw1) * 4 + kg];
    tb.cw[6] = Xu[(size_t)(bd1 + bh1 + zw0) * 4 + kg];
    tb.cw[7] = Xu[(size_t)(bd1 + bh1 + zw1) * 4 + kg];

    tb.gg[0] = gdh00 * gw0;  tb.gg[1] = gdh00 * gw1;
    tb.gg[2] = gdh01 * gw0;  tb.gg[3] = gdh01 * gw1;
    tb.gg[4] = gdh10 * gw0;  tb.gg[5] = gdh10 * gw1;
    tb.gg[6] = gdh11 * gw0;  tb.gg[7] = gdh11 * gw1;
}

__device__ __forceinline__ void tap_consume(
        const Gath& tb, short8 b0, short8 b1, f32x4& acc0, f32x4& acc1)
{
    f32x2 xa0 = {0.f, 0.f}, xa1 = {0.f, 0.f};
    f32x2 xa2 = {0.f, 0.f}, xa3 = {0.f, 0.f};

    #pragma unroll
    for (int e = 0; e < 8; ++e) {
        uint4 cw = tb.cw[e];
        f32x2 g2 = {tb.gg[e], tb.gg[e]};
        f32x2 v0 = {bitsf(cw.x << 16), bitsf(cw.x & 0xFFFF0000u)};
        f32x2 v1 = {bitsf(cw.y << 16), bitsf(cw.y & 0xFFFF0000u)};
        f32x2 v2 = {bitsf(cw.z << 16), bitsf(cw.z & 0xFFFF0000u)};
        f32x2 v3 = {bitsf(cw.w << 16), bitsf(cw.w & 0xFFFF0000u)};
        asm("v_pk_fma_f32 %0, %1, %2, %0" : "+v"(xa0) : "v"(v0), "v"(g2));
        asm("v_pk_fma_f32 %0, %1, %2, %0" : "+v"(xa1) : "v"(v1), "v"(g2));
        asm("v_pk_fma_f32 %0, %1, %2, %0" : "+v"(xa2) : "v"(v2), "v"(g2));
        asm("v_pk_fma_f32 %0, %1, %2, %0" : "+v"(xa3) : "v"(v3), "v"(g2));
    }

    union { unsigned u[4]; short8 s; } av;
    asm("v_cvt_pk_bf16_f32 %0, %1, %2" : "=v"(av.u[0]) : "v"(xa0.x), "v"(xa0.y));
    asm("v_cvt_pk_bf16_f32 %0, %1, %2" : "=v"(av.u[1]) : "v"(xa1.x), "v"(xa1.y));
    asm("v_cvt_pk_bf16_f32 %0, %1, %2" : "=v"(av.u[2]) : "v"(xa2.x), "v"(xa2.y));
    asm("v_cvt_pk_bf16_f32 %0, %1, %2" : "=v"(av.u[3]) : "v"(xa3.x), "v"(xa3.y));

    acc0 = __builtin_amdgcn_mfma_f32_16x16x32_bf16(av.s, b0, acc0, 0, 0, 0);
    acc1 = __builtin_amdgcn_mfma_f32_16x16x32_bf16(av.s, b1, acc1, 0, 0, 0);
}

// ---------------- Fused kernel, M=2 tiles/wave, 3-wave blocks (96 pos)
// Same as r18's best, minus the inter-phase __syncthreads(): offl is purely
// wave-local (indexed by wv only), so same-wave ds_write->ds_read ordering
// (lgkmcnt) suffices. Without the barrier the 3 waves drift, letting one
// wave's phase-1 memory overlap another's phase-3 VALU/MFMA.
__global__ __launch_bounds__(192, 3) void fused_deform14(
        const unsigned short* __restrict__ xT,    // [SPATIAL][32] bf16
        const unsigned short* __restrict__ Bp2,
        const unsigned short* __restrict__ wpk,
        float* __restrict__ out)                  // [32][SPATIAL] f32
{
    __shared__ float offl[3][2][16][82];          // 31.5 KB, wave-local slices

    // bijective XCD swizzle: 768 blocks = 8 XCDs x 96 contiguous
    const int bid  = (int)blockIdx.x;
    const int sbid = (bid & 7) * 96 + (bid >> 3);

    const int tid  = threadIdx.x;
    const int lane = tid & 63, wv = tid >> 6;     // wv in 0..2
    const int p0   = sbid * 96 + wv * 32;
    const int kg   = lane >> 4;
    const int row  = lane & 15;
    const int pos0 = p0 + row;
    const int pos1 = p0 + 16 + row;
    const int w0c = pos0 % WW, h0c = (pos0 / WW) % HH, d0c = pos0 / (WW * HH);
    const int w1c = pos1 % WW, h1c = (pos1 / WW) % HH, d1c = pos1 / (WW * HH);

    const uint4* Xu = (const uint4*)xT;
    const uint4* Bu = (const uint4*)Bp2;
    const uint4* Wu = (const uint4*)wpk;

    // ---------------- phase 1: offset conv, B shared across 2 tiles ----------
    f32x4 cacc0[6], cacc1[6];
    #pragma unroll
    for (int j = 0; j < 6; ++j) {
        cacc0[j] = (f32x4){0.f, 0.f, 0.f, 0.f};
        cacc1[j] = (f32x4){0.f, 0.f, 0.f, 0.f};
    }

    {
        #pragma unroll 1
        for (int n = 0; n < NTAP; ++n) {
            int td = n / 9, th = (n / 3) % 3, tw = n % 3;
            int dis = (td - 1) * 2304 + (th - 1) * 48 + (tw - 1);
            int v0 = ((unsigned)(d0c + td - 1) < DD) & ((unsigned)(h0c + th - 1) < HH)
                   & ((unsigned)(w0c + tw - 1) < WW);
            int v1 = ((unsigned)(d1c + td - 1) < DD) & ((unsigned)(h1c + th - 1) < HH)
                   & ((unsigned)(w1c + tw - 1) < WW);
            uint4 a0 = Xu[(size_t)(v0 ? pos0 + dis : pos0) * 4 + kg];
            uint4 a1 = Xu[(size_t)(v1 ? pos1 + dis : pos1) * 4 + kg];
            uint4 wt[6];
            #pragma unroll
            for (int j = 0; j < 6; ++j)
                wt[j] = Bu[(size_t)(n * 6 + j) * 64 + lane];
            SB0();
            if (!v0) { a0.x = 0; a0.y = 0; a0.z = 0; a0.w = 0; }
            if (!v1) { a1.x = 0; a1.y = 0; a1.z = 0; a1.w = 0; }
            union { uint4 u; short8 s; } av0, av1, b;
            av0.u = a0; av1.u = a1;
            #pragma unroll
            for (int j = 0; j < 6; ++j) {
                b.u = wt[j];
                cacc0[j] = __builtin_amdgcn_mfma_f32_16x16x32_bf16(av0.s, b.s, cacc0[j], 0, 0, 0);
                cacc1[j] = __builtin_amdgcn_mfma_f32_16x16x32_bf16(av1.s, b.s, cacc1[j], 0, 0, 0);
            }
        }
    }

    // ---------------- phase 2: D-frags -> wave-local LDS (no barrier) --------
    #pragma unroll
    for (int j = 0; j < 6; ++j) {
        int col = j * 16 + row;
        if (col < 81) {
            #pragma unroll
            for (int r = 0; r < 4; ++r) {
                offl[wv][0][kg * 4 + r][col] = cacc0[j][r];
                offl[wv][1][kg * 4 + r][col] = cacc1[j][r];
            }
        }
    }
    // NO __syncthreads(): offl[wv] is written and read only by wave wv;
    // the compiler's lgkmcnt wait orders the same-wave ds_write -> ds_read.

    // ---------------- phase 3: gather + einsum, B shared across 2 tiles -------
    const float* ol0 = &offl[wv][0][row][0];
    const float* ol1 = &offl[wv][1][row][0];

    f32x4 acc00 = {0.f, 0.f, 0.f, 0.f}, acc01 = {0.f, 0.f, 0.f, 0.f};
    f32x4 acc10 = {0.f, 0.f, 0.f, 0.f}, acc11 = {0.f, 0.f, 0.f, 0.f};

    {
        Gath g0, g1;
        #pragma unroll 1
        for (int n = 0; n < NTAP; ++n) {
            uint4 wbu0 = Wu[(size_t)(n * 2 + 0) * 64 + lane];
            uint4 wbu1 = Wu[(size_t)(n * 2 + 1) * 64 + lane];
            tap_issue(g0, Xu, ol0[n], ol0[27 + n], ol0[54 + n], n, d0c, h0c, w0c, kg);
            SB0();
            tap_issue(g1, Xu, ol1[n], ol1[27 + n], ol1[54 + n], n, d1c, h1c, w1c, kg);
            SB0();
            union { uint4 u; short8 s; } b0, b1;
            b0.u = wbu0; b1.u = wbu1;
            tap_consume(g0, b0.s, b1.s, acc00, acc01);
            tap_consume(g1, b0.s, b1.s, acc10, acc11);
        }
    }

    // D layout: col = lane&15 -> oc, row = kg*4+reg -> pos
    const int pb0 = p0 + kg * 4;
    const int pb1 = p0 + 16 + kg * 4;
    *(f32x4*)&out[(size_t)row        * SPATIAL + pb0] = acc00;
    *(f32x4*)&out[(size_t)(16 + row) * SPATIAL + pb0] = acc01;
    *(f32x4*)&out[(size_t)row        * SPATIAL + pb1] = acc10;
    *(f32x4*)&out[(size_t)(16 + row) * SPATIAL + pb1] = acc11;
}

// ----------------------------------------------------------------------------
extern "C" void kernel_launch(void* const* d_in, const int* in_sizes, int n_in,
                              void* d_out, int out_size, void* d_ws, size_t ws_size,
                              hipStream_t stream)
{
    const float* x     = (const float*)d_in[0];
    const float* w_off = (const float*)d_in[1];
    const float* w_def = (const float*)d_in[2];
    float* out = (float*)d_out;

    unsigned short* Bp2 = (unsigned short*)((char*)d_ws);
    unsigned short* wpk = (unsigned short*)((char*)d_ws + OFF_WPK);
    unsigned short* xT  = (unsigned short*)((char*)d_ws + OFF_XT);

    prep_all<<<SPATIAL / 64, 256, 0, stream>>>(x, w_off, w_def, Bp2, wpk, xT);
    fused_deform14<<<SPATIAL / 96, 192, 0, stream>>>(xT, Bp2, wpk, out);
}